// Round 2
// baseline (10422.579 us; speedup 1.0000x reference)
//
#include <hip/hip_runtime.h>

#define B_ 64
#define S_ 128
#define NG 4096
#define NP 512

typedef __attribute__((ext_vector_type(8))) short short8;
typedef __attribute__((ext_vector_type(4))) float f32x4;

__device__ inline float bf2f(unsigned short u){
  unsigned int x = ((unsigned int)u) << 16;
  float f; __builtin_memcpy(&f, &x, 4); return f;
}
__device__ inline unsigned short f2bf(float f){
  unsigned int x; __builtin_memcpy(&x, &f, 4);
  x = x + 0x7FFFu + ((x >> 16) & 1u);
  return (unsigned short)(x >> 16);
}

union U16x8 { uint4 u4; short8 s8; };

// fp32 -> bf16 hi/lo split, vectorized x4
__global__ __launch_bounds__(256)
void split_fp32(const float* __restrict__ x,
                unsigned short* __restrict__ hi,
                unsigned short* __restrict__ lo, int n4){
  int i = blockIdx.x * 256 + threadIdx.x;
  if (i >= n4) return;
  float4 v = ((const float4*)x)[i];
  ushort4 h, l;
  h.x = f2bf(v.x); l.x = f2bf(v.x - bf2f(h.x));
  h.y = f2bf(v.y); l.y = f2bf(v.y - bf2f(h.y));
  h.z = f2bf(v.z); l.z = f2bf(v.z - bf2f(h.z));
  h.w = f2bf(v.w); l.w = f2bf(v.w - bf2f(h.w));
  ((ushort4*)hi)[i] = h;
  ((ushort4*)lo)[i] = l;
}

// C[64 x grid*32] = (Ahi+Alo)(64xK) * (Bhi+Blo)(NxK)^T  [+ vx] [relu]
// 3-term bf16 emulation: Ahi*Bhi + Ahi*Blo + Alo*Bhi (fp32 acc).
// 512 threads = 8 waves (4 M-tiles x 2 N-halves), 16x16x32 MFMA.
__global__ __launch_bounds__(512, 1)
void mm3(const unsigned short* __restrict__ Ahi,
         const unsigned short* __restrict__ Alo,
         const unsigned short* __restrict__ Bhi,
         const unsigned short* __restrict__ Blo,
         int K,
         const float* __restrict__ vin, const float* __restrict__ Wih, int s,
         unsigned short* __restrict__ o_hi, unsigned short* __restrict__ o_lo,
         unsigned short* __restrict__ g_hi, unsigned short* __restrict__ g_lo,
         int do_relu)
{
  __shared__ __attribute__((aligned(16))) unsigned short Bth[32 * 264];
  __shared__ __attribute__((aligned(16))) unsigned short Btl[32 * 264];
  const int tid  = threadIdx.x;
  const int lane = tid & 63, wave = tid >> 6;
  const int quad = lane >> 4, l16 = lane & 15;
  const int mw = wave & 3, nw = wave >> 2;
  const int nb = blockIdx.x * 32;
  const int arow = mw * 16 + l16;
  const unsigned short* Ah = Ahi + (size_t)arow * K;
  const unsigned short* Al = Alo + (size_t)arow * K;
  f32x4 acc = {0.f, 0.f, 0.f, 0.f};
  const int nchunks = K >> 8;
  for (int kc = 0; kc < nchunks; ++kc){
    #pragma unroll
    for (int t = 0; t < 2; ++t){
      int c = tid + t * 512;            // 1024 x 16B chunks per tile
      int row = c >> 5, ko = (c & 31) << 3;
      size_t off = (size_t)(nb + row) * K + (kc << 8) + ko;
      *(uint4*)&Bth[row * 264 + ko] = *(const uint4*)(Bhi + off);
      *(uint4*)&Btl[row * 264 + ko] = *(const uint4*)(Blo + off);
    }
    __syncthreads();
    #pragma unroll
    for (int ki = 0; ki < 8; ++ki){
      U16x8 bh, bl, ah, al;
      int ldso = (nw * 16 + l16) * 264 + ki * 32 + quad * 8;
      bh.u4 = *(const uint4*)&Bth[ldso];
      bl.u4 = *(const uint4*)&Btl[ldso];
      size_t ao = (size_t)(kc << 8) + ki * 32 + quad * 8;
      ah.u4 = *(const uint4*)(Ah + ao);
      al.u4 = *(const uint4*)(Al + ao);
      acc = __builtin_amdgcn_mfma_f32_16x16x32_bf16(ah.s8, bh.s8, acc, 0, 0, 0);
      acc = __builtin_amdgcn_mfma_f32_16x16x32_bf16(ah.s8, bl.s8, acc, 0, 0, 0);
      acc = __builtin_amdgcn_mfma_f32_16x16x32_bf16(al.s8, bh.s8, acc, 0, 0, 0);
    }
    __syncthreads();
  }
  // D[row = quad*4+r][col = l16]
  const int n = nb + nw * 16 + l16;
  float wi0 = 0.f, wi1 = 0.f;
  if (vin){
    float2 wp = *(const float2*)(Wih + 2 * (size_t)n);
    wi0 = wp.x; wi1 = wp.y;
  }
  #pragma unroll
  for (int r = 0; r < 4; ++r){
    int m = mw * 16 + quad * 4 + r;
    float val = acc[r];
    if (vin){
      float2 vp = *(const float2*)(vin + 2 * ((size_t)m * S_ + s));
      val += vp.x * wi0 + vp.y * wi1;
    }
    if (do_relu) val = fmaxf(val, 0.f);
    size_t idx = (size_t)m * NG + n;
    unsigned short hh = f2bf(val);
    unsigned short ll = f2bf(val - bf2f(hh));
    o_hi[idx] = hh;
    o_lo[idx] = ll;
    if (g_hi){ g_hi[idx] = hh; g_lo[idx] = ll; }
  }
}

// out[(b*S+s)*NP+p] = G[slot][b][:] dot Wd[p][:]; grid=(NP/32, chunk_len)
__global__ __launch_bounds__(512, 1)
void decode3(const unsigned short* __restrict__ Gbase,   // slots of hi(262144)+lo(262144)
             const unsigned short* __restrict__ Bhi,
             const unsigned short* __restrict__ Blo,
             float* __restrict__ out, int s_base)
{
  __shared__ __attribute__((aligned(16))) unsigned short Bth[32 * 264];
  __shared__ __attribute__((aligned(16))) unsigned short Btl[32 * 264];
  const int tid  = threadIdx.x;
  const int lane = tid & 63, wave = tid >> 6;
  const int quad = lane >> 4, l16 = lane & 15;
  const int mw = wave & 3, nw = wave >> 2;
  const int nb = blockIdx.x * 32;
  const unsigned short* slot = Gbase + (size_t)blockIdx.y * 524288;
  const int arow = mw * 16 + l16;
  const unsigned short* Ah = slot + (size_t)arow * NG;
  const unsigned short* Al = slot + 262144 + (size_t)arow * NG;
  f32x4 acc = {0.f, 0.f, 0.f, 0.f};
  for (int kc = 0; kc < (NG >> 8); ++kc){
    #pragma unroll
    for (int t = 0; t < 2; ++t){
      int c = tid + t * 512;
      int row = c >> 5, ko = (c & 31) << 3;
      size_t off = (size_t)(nb + row) * NG + (kc << 8) + ko;
      *(uint4*)&Bth[row * 264 + ko] = *(const uint4*)(Bhi + off);
      *(uint4*)&Btl[row * 264 + ko] = *(const uint4*)(Blo + off);
    }
    __syncthreads();
    #pragma unroll
    for (int ki = 0; ki < 8; ++ki){
      U16x8 bh, bl, ah, al;
      int ldso = (nw * 16 + l16) * 264 + ki * 32 + quad * 8;
      bh.u4 = *(const uint4*)&Bth[ldso];
      bl.u4 = *(const uint4*)&Btl[ldso];
      size_t ao = (size_t)(kc << 8) + ki * 32 + quad * 8;
      ah.u4 = *(const uint4*)(Ah + ao);
      al.u4 = *(const uint4*)(Al + ao);
      acc = __builtin_amdgcn_mfma_f32_16x16x32_bf16(ah.s8, bh.s8, acc, 0, 0, 0);
      acc = __builtin_amdgcn_mfma_f32_16x16x32_bf16(ah.s8, bl.s8, acc, 0, 0, 0);
      acc = __builtin_amdgcn_mfma_f32_16x16x32_bf16(al.s8, bh.s8, acc, 0, 0, 0);
    }
    __syncthreads();
  }
  const int p = nb + nw * 16 + l16;
  const int s = s_base + blockIdx.y;
  #pragma unroll
  for (int r = 0; r < 4; ++r){
    int b = mw * 16 + quad * 4 + r;
    out[((size_t)b * S_ + s) * NP + p] = acc[r];
  }
}

extern "C" void kernel_launch(void* const* d_in, const int* in_sizes, int n_in,
                              void* d_out, int out_size, void* d_ws, size_t ws_size,
                              hipStream_t stream) {
  const float* v    = (const float*)d_in[0]; // (64,128,2)
  const float* p0   = (const float*)d_in[1]; // (64,512)
  const float* Wini = (const float*)d_in[2]; // (4096,512)
  const float* Wih  = (const float*)d_in[3]; // (4096,2)
  const float* Whh  = (const float*)d_in[4]; // (4096,4096)
  const float* Wdec = (const float*)d_in[5]; // (512,4096)
  float* out = (float*)d_out;
  unsigned short* ws = (unsigned short*)d_ws;

  // workspace layout (element offsets in ushort)
  unsigned short* WhhHI = ws;                       // 16777216
  unsigned short* WhhLO = ws + 16777216;
  unsigned short* WdeHI = ws + 33554432;            // 2097152
  unsigned short* WdeLO = ws + 35651584;
  unsigned short* WinHI = ws + 37748736;            // 2097152
  unsigned short* WinLO = ws + 39845888;
  unsigned short* p0HI  = ws + 41943040;            // 32768
  unsigned short* p0LO  = ws + 41975808;
  const size_t HN = (size_t)B_ * NG;                // 262144
  unsigned short* h_hi[2] = { ws + 42008576,            ws + 42008576 + HN };
  unsigned short* h_lo[2] = { ws + 42008576 + 2*HN,     ws + 42008576 + 3*HN };
  unsigned short* Gbase   = ws + 43057152;          // slots of 524288 (hi+lo)

  long long slots = ((long long)(ws_size / 2) - 43057152LL) / 524288LL;
  int Sc = (int)slots; if (Sc > S_) Sc = S_; if (Sc < 1) Sc = 1;

  dim3 blk(512);
  split_fp32<<<dim3((16777216/4 + 255)/256), 256, 0, stream>>>(Whh,  WhhHI, WhhLO, 16777216/4);
  split_fp32<<<dim3((2097152/4  + 255)/256), 256, 0, stream>>>(Wdec, WdeHI, WdeLO, 2097152/4);
  split_fp32<<<dim3((2097152/4  + 255)/256), 256, 0, stream>>>(Wini, WinHI, WinLO, 2097152/4);
  split_fp32<<<dim3((32768/4    + 255)/256), 256, 0, stream>>>(p0,   p0HI,  p0LO,  32768/4);

  // h0 = p0 @ W_init^T (no vx, no relu, no G)
  mm3<<<dim3(NG/32), blk, 0, stream>>>(p0HI, p0LO, WinHI, WinLO, NP,
                                       nullptr, nullptr, 0,
                                       h_hi[0], h_lo[0], nullptr, nullptr, 0);
  int cur = 0, chunk_start = 0;
  for (int s = 0; s < S_; ++s){
    int nxt = cur ^ 1;
    int slot = s - chunk_start;
    mm3<<<dim3(NG/32), blk, 0, stream>>>(h_hi[cur], h_lo[cur], WhhHI, WhhLO, NG,
                                         v, Wih, s,
                                         h_hi[nxt], h_lo[nxt],
                                         Gbase + (size_t)slot * 524288,
                                         Gbase + (size_t)slot * 524288 + HN, 1);
    cur = nxt;
    if (slot + 1 == Sc || s == S_ - 1){
      int len = slot + 1;
      decode3<<<dim3(NP/32, len), blk, 0, stream>>>(Gbase, WdeHI, WdeLO, out, chunk_start);
      chunk_start = s + 1;
    }
  }
}

// Round 3
// 9980.101 us; speedup vs baseline: 1.0443x; 1.0443x over previous
//
#include <hip/hip_runtime.h>

#define B_ 64
#define S_ 128
#define NG 4096
#define NP 512

typedef __attribute__((ext_vector_type(8))) short short8;
typedef __attribute__((ext_vector_type(4))) float f32x4;

__device__ inline float bf2f(unsigned short u){
  unsigned int x = ((unsigned int)u) << 16;
  float f; __builtin_memcpy(&f, &x, 4); return f;
}
__device__ inline unsigned short f2bf(float f){
  unsigned int x; __builtin_memcpy(&x, &f, 4);
  x = x + 0x7FFFu + ((x >> 16) & 1u);
  return (unsigned short)(x >> 16);
}

union U16x8 { uint4 u4; short8 s8; };

__global__ __launch_bounds__(256)
void split_fp32(const float* __restrict__ x,
                unsigned short* __restrict__ hi,
                unsigned short* __restrict__ lo, int n4){
  int i = blockIdx.x * 256 + threadIdx.x;
  if (i >= n4) return;
  float4 v = ((const float4*)x)[i];
  ushort4 h, l;
  h.x = f2bf(v.x); l.x = f2bf(v.x - bf2f(h.x));
  h.y = f2bf(v.y); l.y = f2bf(v.y - bf2f(h.y));
  h.z = f2bf(v.z); l.z = f2bf(v.z - bf2f(h.z));
  h.w = f2bf(v.w); l.w = f2bf(v.w - bf2f(h.w));
  ((ushort4*)hi)[i] = h;
  ((ushort4*)lo)[i] = l;
}

// C[64 x grid*32] = (Ahi+Alo)(64xK)*(Bhi+Blo)(NxK)^T [+vx][relu]
// 3-term bf16 emu. 512 thr = 8 waves (4 M x 2 N). BK=128, double-buffered LDS,
// register prefetch, ONE barrier per K-chunk.
__global__ __launch_bounds__(512, 2)
void mm3_step(const unsigned short* __restrict__ Ahi,
              const unsigned short* __restrict__ Alo,
              const unsigned short* __restrict__ Bhi,
              const unsigned short* __restrict__ Blo,
              int K,
              const float* __restrict__ vin, const float* __restrict__ Wih, int s,
              unsigned short* __restrict__ o_hi, unsigned short* __restrict__ o_lo,
              unsigned short* __restrict__ g_hi, int do_relu)
{
  // pitch 132 shorts = 66 dwords == 2 mod 32 -> 2-way bank alias (free)
  __shared__ __attribute__((aligned(16))) unsigned short Bth[2][32*132];
  __shared__ __attribute__((aligned(16))) unsigned short Btl[2][32*132];
  const int tid  = threadIdx.x;
  const int lane = tid & 63, wave = tid >> 6;
  const int quad = lane >> 4, l16 = lane & 15;
  const int mw = wave & 3, nw = wave >> 2;
  const int nb = blockIdx.x * 32;
  const int arow = mw * 16 + l16;
  const unsigned short* Ah = Ahi + (size_t)arow * K;
  const unsigned short* Al = Alo + (size_t)arow * K;
  const int srow = tid >> 4;            // 0..31
  const int sko  = (tid & 15) << 3;     // 0..120
  const unsigned short* Bh0 = Bhi + (size_t)(nb + srow) * K + sko;
  const unsigned short* Bl0 = Blo + (size_t)(nb + srow) * K + sko;
  const int nchunks = K >> 7;
  f32x4 acc = {0.f, 0.f, 0.f, 0.f};

  uint4 ph = *(const uint4*)Bh0;
  uint4 pl = *(const uint4*)Bl0;
  *(uint4*)&Bth[0][srow * 132 + sko] = ph;
  *(uint4*)&Btl[0][srow * 132 + sko] = pl;
  __syncthreads();

  for (int kc = 0; kc < nchunks; ++kc){
    const int cur = kc & 1;
    const bool more = (kc + 1 < nchunks);
    if (more){
      ph = *(const uint4*)(Bh0 + ((size_t)(kc + 1) << 7));
      pl = *(const uint4*)(Bl0 + ((size_t)(kc + 1) << 7));
    }
    #pragma unroll
    for (int ki = 0; ki < 4; ++ki){
      U16x8 bh, bl, ah, al;
      const int lo_ = (nw * 16 + l16) * 132 + ki * 32 + quad * 8;
      bh.u4 = *(const uint4*)&Bth[cur][lo_];
      bl.u4 = *(const uint4*)&Btl[cur][lo_];
      const size_t ao = ((size_t)kc << 7) + ki * 32 + quad * 8;
      ah.u4 = *(const uint4*)(Ah + ao);
      al.u4 = *(const uint4*)(Al + ao);
      acc = __builtin_amdgcn_mfma_f32_16x16x32_bf16(ah.s8, bh.s8, acc, 0, 0, 0);
      acc = __builtin_amdgcn_mfma_f32_16x16x32_bf16(ah.s8, bl.s8, acc, 0, 0, 0);
      acc = __builtin_amdgcn_mfma_f32_16x16x32_bf16(al.s8, bh.s8, acc, 0, 0, 0);
    }
    if (more){
      *(uint4*)&Bth[cur ^ 1][srow * 132 + sko] = ph;
      *(uint4*)&Btl[cur ^ 1][srow * 132 + sko] = pl;
      __syncthreads();
    }
  }
  // D[row = quad*4+r][col = l16]
  const int n = nb + nw * 16 + l16;
  float wi0 = 0.f, wi1 = 0.f;
  if (vin){
    float2 wp = *(const float2*)(Wih + 2 * (size_t)n);
    wi0 = wp.x; wi1 = wp.y;
  }
  #pragma unroll
  for (int r = 0; r < 4; ++r){
    int m = mw * 16 + quad * 4 + r;
    float val = acc[r];
    if (vin){
      float2 vp = *(const float2*)(vin + 2 * ((size_t)m * S_ + s));
      val += vp.x * wi0 + vp.y * wi1;
    }
    if (do_relu) val = fmaxf(val, 0.f);
    size_t idx = (size_t)m * NG + n;
    unsigned short hh = f2bf(val);
    o_hi[idx] = hh;
    o_lo[idx] = f2bf(val - bf2f(hh));
    if (g_hi) g_hi[idx] = hh;
  }
}

// out = G(chunk_len*64 x 4096, hi-only) * (Whi+Wlo)(512x4096)^T   [2-term]
// grid (len*64/128, 4), block 256 = 4 waves (2x2), wave tile 64x64 = 4x4 of 16x16
__global__ __launch_bounds__(256, 1)
void decode2(const unsigned short* __restrict__ G,
             const unsigned short* __restrict__ Whi,
             const unsigned short* __restrict__ Wlo,
             float* __restrict__ out, int s_base)
{
  // pitch 72 shorts = 36 dwords == 4 mod 32 -> 2-way alias (free)
  __shared__ __attribute__((aligned(16))) unsigned short Alds[128*72];
  __shared__ __attribute__((aligned(16))) unsigned short Bhds[128*72];
  __shared__ __attribute__((aligned(16))) unsigned short Blds[128*72];
  const int tid  = threadIdx.x;
  const int lane = tid & 63, wave = tid >> 6;
  const int quad = lane >> 4, l16 = lane & 15;
  const int wm = wave & 1, wn = wave >> 1;
  const size_t m0 = (size_t)blockIdx.x * 128;
  const int n0 = blockIdx.y * 128;
  f32x4 acc[4][4];
  #pragma unroll
  for (int a = 0; a < 4; ++a)
    #pragma unroll
    for (int b = 0; b < 4; ++b) acc[a][b] = (f32x4){0.f,0.f,0.f,0.f};

  uint4 pa[4], pbh[4], pbl[4];
  #pragma unroll
  for (int t = 0; t < 4; ++t){
    int q = tid + t * 256, row = q >> 3, ko = (q & 7) << 3;
    pa[t]  = *(const uint4*)(G   + (m0 + row) * 4096 + ko);
    pbh[t] = *(const uint4*)(Whi + (size_t)(n0 + row) * 4096 + ko);
    pbl[t] = *(const uint4*)(Wlo + (size_t)(n0 + row) * 4096 + ko);
  }
  for (int kc = 0; kc < 64; ++kc){
    if (kc) __syncthreads();            // prev-iter reads done
    #pragma unroll
    for (int t = 0; t < 4; ++t){
      int q = tid + t * 256, row = q >> 3, ko = (q & 7) << 3;
      *(uint4*)&Alds[row * 72 + ko] = pa[t];
      *(uint4*)&Bhds[row * 72 + ko] = pbh[t];
      *(uint4*)&Blds[row * 72 + ko] = pbl[t];
    }
    __syncthreads();
    if (kc + 1 < 64){
      #pragma unroll
      for (int t = 0; t < 4; ++t){
        int q = tid + t * 256, row = q >> 3, ko = (q & 7) << 3;
        size_t kbase = (size_t)(kc + 1) * 64 + ko;
        pa[t]  = *(const uint4*)(G   + (m0 + row) * 4096 + kbase);
        pbh[t] = *(const uint4*)(Whi + (size_t)(n0 + row) * 4096 + kbase);
        pbl[t] = *(const uint4*)(Wlo + (size_t)(n0 + row) * 4096 + kbase);
      }
    }
    #pragma unroll
    for (int ks = 0; ks < 2; ++ks){
      U16x8 af[4], bhf[4], blf[4];
      #pragma unroll
      for (int tm = 0; tm < 4; ++tm)
        af[tm].u4 = *(const uint4*)&Alds[(wm*64 + tm*16 + l16)*72 + ks*32 + quad*8];
      #pragma unroll
      for (int tn = 0; tn < 4; ++tn){
        bhf[tn].u4 = *(const uint4*)&Bhds[(wn*64 + tn*16 + l16)*72 + ks*32 + quad*8];
        blf[tn].u4 = *(const uint4*)&Blds[(wn*64 + tn*16 + l16)*72 + ks*32 + quad*8];
      }
      #pragma unroll
      for (int tm = 0; tm < 4; ++tm)
        #pragma unroll
        for (int tn = 0; tn < 4; ++tn){
          acc[tm][tn] = __builtin_amdgcn_mfma_f32_16x16x32_bf16(af[tm].s8, bhf[tn].s8, acc[tm][tn], 0, 0, 0);
          acc[tm][tn] = __builtin_amdgcn_mfma_f32_16x16x32_bf16(af[tm].s8, blf[tn].s8, acc[tm][tn], 0, 0, 0);
        }
    }
  }
  #pragma unroll
  for (int tm = 0; tm < 4; ++tm){
    #pragma unroll
    for (int tn = 0; tn < 4; ++tn){
      int p = n0 + wn * 64 + tn * 16 + l16;
      #pragma unroll
      for (int r = 0; r < 4; ++r){
        int m = (int)m0 + wm * 64 + tm * 16 + quad * 4 + r;  // m within full chunk? no: m0 is global chunk row
        int slot = m >> 6, b = m & 63;
        out[((size_t)b * S_ + s_base + slot) * NP + p] = acc[tm][tn][r];
      }
    }
  }
}

extern "C" void kernel_launch(void* const* d_in, const int* in_sizes, int n_in,
                              void* d_out, int out_size, void* d_ws, size_t ws_size,
                              hipStream_t stream) {
  const float* v    = (const float*)d_in[0];
  const float* p0   = (const float*)d_in[1];
  const float* Wini = (const float*)d_in[2];
  const float* Wih  = (const float*)d_in[3];
  const float* Whh  = (const float*)d_in[4];
  const float* Wdec = (const float*)d_in[5];
  float* out = (float*)d_out;
  unsigned short* ws = (unsigned short*)d_ws;

  unsigned short* WhhHI = ws;                       // 16777216
  unsigned short* WhhLO = ws + 16777216;
  unsigned short* WdeHI = ws + 33554432;            // 2097152
  unsigned short* WdeLO = ws + 35651584;
  unsigned short* WinHI = ws + 37748736;            // 2097152
  unsigned short* WinLO = ws + 39845888;
  unsigned short* p0HI  = ws + 41943040;            // 32768
  unsigned short* p0LO  = ws + 41975808;
  const size_t HN = (size_t)B_ * NG;                // 262144
  unsigned short* h_hi[2] = { ws + 42008576,          ws + 42008576 + HN };
  unsigned short* h_lo[2] = { ws + 42008576 + 2*HN,   ws + 42008576 + 3*HN };
  unsigned short* Gbase   = ws + 43057152;          // hi-only slabs of 262144

  long long slots = ((long long)(ws_size / 2) - 43057152LL) / 262144LL;
  int Sc = (int)slots;
  if (Sc > S_) Sc = S_;
  Sc &= ~1;                 // even -> all chunk lens even -> M % 128 == 0
  if (Sc < 2) Sc = 2;

  split_fp32<<<dim3(16777216/4/256), 256, 0, stream>>>(Whh,  WhhHI, WhhLO, 16777216/4);
  split_fp32<<<dim3(2097152/4/256),  256, 0, stream>>>(Wdec, WdeHI, WdeLO, 2097152/4);
  split_fp32<<<dim3(2097152/4/256),  256, 0, stream>>>(Wini, WinHI, WinLO, 2097152/4);
  split_fp32<<<dim3(32768/4/256),    256, 0, stream>>>(p0,   p0HI,  p0LO,  32768/4);

  mm3_step<<<dim3(NG/32), dim3(512), 0, stream>>>(p0HI, p0LO, WinHI, WinLO, NP,
                                                  nullptr, nullptr, 0,
                                                  h_hi[0], h_lo[0], nullptr, 0);
  int cur = 0, chunk_start = 0;
  for (int s = 0; s < S_; ++s){
    int nxt = cur ^ 1;
    int slot = s - chunk_start;
    mm3_step<<<dim3(NG/32), dim3(512), 0, stream>>>(h_hi[cur], h_lo[cur], WhhHI, WhhLO, NG,
                                                    v, Wih, s,
                                                    h_hi[nxt], h_lo[nxt],
                                                    Gbase + (size_t)slot * HN, 1);
    cur = nxt;
    if (slot + 1 == Sc || s == S_ - 1){
      int len = slot + 1;                // even
      decode2<<<dim3(len * 64 / 128, NP / 128), dim3(256), 0, stream>>>(
          Gbase, WdeHI, WdeLO, out, chunk_start);
      chunk_start = s + 1;
    }
  }
}